// Round 1
// baseline (207.809 us; speedup 1.0000x reference)
//
#include <hip/hip_runtime.h>

#define NODES 10000
#define BATCH 8
#define CH    128
#define KNB   16
#define CO    256

typedef __bf16 bf16x8 __attribute__((ext_vector_type(8)));
typedef float  f32x4  __attribute__((ext_vector_type(4)));

__device__ __forceinline__ unsigned short f2bf(float f) {
  unsigned u = __float_as_uint(f);
  u = (u + 0x7FFFu + ((u >> 16) & 1u)) >> 16;   // RNE
  return (unsigned short)u;
}

// max of packed non-negative bf16 == packed u16 max (relu guarantees >=0)
__device__ __forceinline__ unsigned pkmax(unsigned a, unsigned b) {
  unsigned d;
  asm("v_pk_max_u16 %0, %1, %2" : "=v"(d) : "v"(a), "v"(b));
  return d;
}
__device__ __forceinline__ uint4 pkmax4(uint4 a, uint4 b) {
  a.x = pkmax(a.x, b.x); a.y = pkmax(a.y, b.y);
  a.z = pkmax(a.z, b.z); a.w = pkmax(a.w, b.w);
  return a;
}
__device__ __forceinline__ bf16x8 asbf8(uint4 u) {
  union { uint4 u; bf16x8 b; } c; c.u = u; return c.b;
}

// ---------------------------------------------------------------------------
// fp32 -> bf16 weight conversion (row-major [d][k] kept)
// ---------------------------------------------------------------------------
__global__ __launch_bounds__(256) void prep(
    const float* __restrict__ W1, const float* __restrict__ Wp,
    const float* __restrict__ W2,
    unsigned short* __restrict__ W1b, unsigned short* __restrict__ Wpb,
    unsigned short* __restrict__ W2b)
{
  int i = blockIdx.x * 256 + threadIdx.x;   // float4 index, 24576 total
  const float* src; unsigned short* dst; int off;
  if (i < 4096)      { src = W1; dst = W1b; off = i; }
  else if (i < 8192) { src = Wp; dst = Wpb; off = i - 4096; }
  else               { src = W2; dst = W2b; off = i - 8192; }
  float4 v = ((const float4*)src)[off];
  ushort4 o;
  o.x = f2bf(v.x); o.y = f2bf(v.y); o.z = f2bf(v.z); o.w = f2bf(v.w);
  ((ushort4*)dst)[off] = o;
}

// ---------------------------------------------------------------------------
// Fused: h = relu(W1 x + b1); z = relu(Wp h + bp). Both written node-major
// bf16 [b][n][128]. Block: 256 thr / 4 waves, 64-node tile, K=128 one shot.
// (unchanged this round — need its counters next round)
// ---------------------------------------------------------------------------
__global__ __launch_bounds__(256) void fused_hz(
    const unsigned short* __restrict__ W1b, const float* __restrict__ b1,
    const unsigned short* __restrict__ Wpb, const float* __restrict__ bp,
    const float* __restrict__ x,
    unsigned short* __restrict__ h_t, unsigned short* __restrict__ z_t)
{
  const int b  = blockIdx.y;
  const int n0 = blockIdx.x * 64;
  const int t  = threadIdx.x;
  const int lane = t & 63, w = t >> 6;
  const int lm = lane & 15, q = lane >> 4;

  __shared__ __align__(16) unsigned short Bt[64 * 128];   // x tile, 16 KB
  __shared__ __align__(16) unsigned short Ht[64 * 128];   // h tile, 16 KB
  char* BtB = (char*)Bt;
  char* HtB = (char*)Ht;

  // ---- stage x: fp32 [b][c][n] -> bf16 [n][c], XOR-swizzled 16B chunks
  {
    const float* X = x + (size_t)b * CH * NODES;
#pragma unroll
    for (int rep = 0; rep < 4; ++rep) {
      int flat = t + rep * 256;
      int c2 = flat >> 4, n4 = flat & 15;
      int c  = c2 * 2;
      int gn = n0 + n4 * 4;
      float4 a0 = make_float4(0.f,0.f,0.f,0.f), a1 = a0;
      if (gn < NODES) {
        a0 = *(const float4*)(X + (size_t)c * NODES + gn);
        a1 = *(const float4*)(X + (size_t)(c + 1) * NODES + gn);
      }
      float v0[4] = {a0.x, a0.y, a0.z, a0.w};
      float v1[4] = {a1.x, a1.y, a1.z, a1.w};
#pragma unroll
      for (int i = 0; i < 4; ++i) {
        int nn = n4 * 4 + i;
        unsigned pk = (unsigned)f2bf(v0[i]) | ((unsigned)f2bf(v1[i]) << 16);
        int phys = nn * 256 + (((c2 >> 2) ^ (nn & 7)) << 4) + ((c2 & 3) << 2);
        *(unsigned*)(BtB + phys) = pk;
      }
    }
  }

  const int d0  = (w & 1) * 64;      // d-half for this wave
  const int nbw = (w >> 1) * 32;     // node-pair base

  // W1 A-fragments (global, L2-hot)
  uint4 af[4][4];
#pragma unroll
  for (int dt = 0; dt < 4; ++dt)
#pragma unroll
    for (int kt = 0; kt < 4; ++kt)
      af[dt][kt] = *(const uint4*)(W1b + (d0 + dt*16 + lm) * CH + kt*32 + q*8);

  __syncthreads();

  // ---- phase 1 MFMA: h-tile
  f32x4 acc[4][2];
#pragma unroll
  for (int dt = 0; dt < 4; ++dt)
#pragma unroll
    for (int nt = 0; nt < 2; ++nt) acc[dt][nt] = (f32x4){0.f,0.f,0.f,0.f};

#pragma unroll
  for (int kt = 0; kt < 4; ++kt)
#pragma unroll
    for (int nt = 0; nt < 2; ++nt) {
      int nl = nbw + nt * 16 + lm;
      int chunk = kt * 4 + q;
      int phys = nl * 256 + ((chunk ^ (nl & 7)) << 4);
      bf16x8 bb = asbf8(*(const uint4*)(BtB + phys));
#pragma unroll
      for (int dt = 0; dt < 4; ++dt)
        acc[dt][nt] = __builtin_amdgcn_mfma_f32_16x16x32_bf16(
            asbf8(af[dt][kt]), bb, acc[dt][nt], 0, 0, 0);
    }

  // Wp A-fragments for phase 2 (issue loads before the barrier)
  uint4 af2[4][4];
#pragma unroll
  for (int dt = 0; dt < 4; ++dt)
#pragma unroll
    for (int kt = 0; kt < 4; ++kt)
      af2[dt][kt] = *(const uint4*)(Wpb + (d0 + dt*16 + lm) * CH + kt*32 + q*8);

  // ---- epilogue 1: bias+relu+bf16 -> h_t global + Ht LDS (B-frag layout)
#pragma unroll
  for (int dt = 0; dt < 4; ++dt) {
    int dbase = d0 + dt * 16 + q * 4;
    float4 bi = *(const float4*)(b1 + dbase);
    float bv[4] = {bi.x, bi.y, bi.z, bi.w};
#pragma unroll
    for (int nt = 0; nt < 2; ++nt) {
      int nl = nbw + nt * 16 + lm;
      int gn = n0 + nl;
      ushort4 o;
      o.x = f2bf(fmaxf(acc[dt][nt][0] + bv[0], 0.f));
      o.y = f2bf(fmaxf(acc[dt][nt][1] + bv[1], 0.f));
      o.z = f2bf(fmaxf(acc[dt][nt][2] + bv[2], 0.f));
      o.w = f2bf(fmaxf(acc[dt][nt][3] + bv[3], 0.f));
      int chunk = dbase >> 3;
      int phys  = nl * 256 + ((chunk ^ (nl & 7)) << 4) + ((q & 1) << 3);
      *(ushort4*)(HtB + phys) = o;
      if (gn < NODES)
        *(ushort4*)(h_t + ((size_t)b * NODES + gn) * CH + dbase) = o;
    }
  }

  __syncthreads();

  // ---- phase 2 MFMA: z-tile from Ht
#pragma unroll
  for (int dt = 0; dt < 4; ++dt)
#pragma unroll
    for (int nt = 0; nt < 2; ++nt) acc[dt][nt] = (f32x4){0.f,0.f,0.f,0.f};

#pragma unroll
  for (int kt = 0; kt < 4; ++kt)
#pragma unroll
    for (int nt = 0; nt < 2; ++nt) {
      int nl = nbw + nt * 16 + lm;
      int chunk = kt * 4 + q;
      int phys = nl * 256 + ((chunk ^ (nl & 7)) << 4);
      bf16x8 bb = asbf8(*(const uint4*)(HtB + phys));
#pragma unroll
      for (int dt = 0; dt < 4; ++dt)
        acc[dt][nt] = __builtin_amdgcn_mfma_f32_16x16x32_bf16(
            asbf8(af2[dt][kt]), bb, acc[dt][nt], 0, 0, 0);
    }

  // ---- epilogue 2 -> z_t global
#pragma unroll
  for (int dt = 0; dt < 4; ++dt) {
    int dbase = d0 + dt * 16 + q * 4;
    float4 bi = *(const float4*)(bp + dbase);
    float bv[4] = {bi.x, bi.y, bi.z, bi.w};
#pragma unroll
    for (int nt = 0; nt < 2; ++nt) {
      int gn = n0 + nbw + nt * 16 + lm;
      if (gn < NODES) {
        ushort4 o;
        o.x = f2bf(fmaxf(acc[dt][nt][0] + bv[0], 0.f));
        o.y = f2bf(fmaxf(acc[dt][nt][1] + bv[1], 0.f));
        o.z = f2bf(fmaxf(acc[dt][nt][2] + bv[2], 0.f));
        o.w = f2bf(fmaxf(acc[dt][nt][3] + bv[3], 0.f));
        *(ushort4*)(z_t + ((size_t)b * NODES + gn) * CH + dbase) = o;
      }
    }
  }
}

// ---------------------------------------------------------------------------
// gmax_kernel: zm[b][n][128] = max_k z[b][idx[n,k]][128].
// Barrier-free, LDS-free, low-VGPR -> gather latency hidden by occupancy
// (the fused predecessor was capped at 4 blocks/CU by its 36KB LDS).
// Quad (nl = t>>2, c = t&3) owns one node; thread covers chunks c*16+cg*64
// so every quad read/write is a 64B-coalesced L2 transaction. b = bid&7
// keeps each batch's 2.56MB z slab XCD-affine.
// ---------------------------------------------------------------------------
__global__ __launch_bounds__(256) void gmax_kernel(
    const unsigned short* __restrict__ z_t, const int* __restrict__ e0,
    unsigned short* __restrict__ zm)
{
  const int bid = blockIdx.x;
  const int b   = bid & 7;
  const int n0  = (bid >> 3) * 64;
  const int t   = threadIdx.x;
  const int nl  = t >> 2, c = t & 3;
  const int gn  = n0 + nl;
  if (gn >= NODES) return;          // no barrier in this kernel: safe

  const int* ip = e0 + ((size_t)b * NODES + gn) * KNB;
  int4 iv0 = *(const int4*)(ip);
  int4 iv1 = *(const int4*)(ip + 4);
  int4 iv2 = *(const int4*)(ip + 8);
  int4 iv3 = *(const int4*)(ip + 12);
  int idx[16] = {iv0.x, iv0.y, iv0.z, iv0.w,
                 iv1.x, iv1.y, iv1.z, iv1.w,
                 iv2.x, iv2.y, iv2.z, iv2.w,
                 iv3.x, iv3.y, iv3.z, iv3.w};

  const char* Z = (const char*)(z_t + (size_t)b * NODES * CH) + c * 16;
  uint4 m[4];
#pragma unroll
  for (int cg = 0; cg < 4; ++cg) m[cg] = make_uint4(0u, 0u, 0u, 0u);

#pragma unroll
  for (int k = 0; k < KNB; ++k) {
    const char* p = Z + (size_t)idx[k] * (CH * 2);
#pragma unroll
    for (int cg = 0; cg < 4; ++cg)
      m[cg] = pkmax4(m[cg], *(const uint4*)(p + cg * 64));
  }

  char* O = (char*)(zm + ((size_t)b * NODES + gn) * CH) + c * 16;
#pragma unroll
  for (int cg = 0; cg < 4; ++cg)
    *(uint4*)(O + cg * 64) = m[cg];
}

// ---------------------------------------------------------------------------
// out_gemm: out[b][d][n] = relu(W2 @ [h[n]; zm[n]] + b2), d=256, K=256.
// Pure streaming GEMM: both cat halves are contiguous node-major bf16 reads
// (no gather, no idx LDS -> 32KB LDS, 5 blocks/CU LDS-wise). XOR-swizzled
// tile for conflict-free ds_read_b128; W2 A-frags double-buffered from L2.
// ---------------------------------------------------------------------------
__global__ __launch_bounds__(256) void out_gemm(
    const unsigned short* __restrict__ h_t, const unsigned short* __restrict__ zm,
    const unsigned short* __restrict__ W2b, const float* __restrict__ b2,
    float* __restrict__ out)
{
  const int bid = blockIdx.x;
  const int b   = bid & 7;
  const int n0  = (bid >> 3) * 64;
  const int t   = threadIdx.x;
  const int lane = t & 63, w = t >> 6;
  const int lm = lane & 15, q = lane >> 4;

  __shared__ __align__(16) unsigned short cat[64 * 256];  // 32 KB, swizzled
  char* catB = (char*)cat;

  // ---- stage h (chunks 0-15) + zmax (chunks 16-31): 256B contiguous runs
#pragma unroll
  for (int rep = 0; rep < 8; ++rep) {
    int flat = t + rep * 256;           // 0..2047
    int nl = flat >> 5, chunk = flat & 31;
    int gn = n0 + nl;
    uint4 v = make_uint4(0u, 0u, 0u, 0u);
    if (gn < NODES) {
      const unsigned short* src = (chunk < 16)
        ? h_t + ((size_t)b * NODES + gn) * CH + chunk * 8
        : zm  + ((size_t)b * NODES + gn) * CH + (chunk - 16) * 8;
      v = *(const uint4*)src;
    }
    int phys = nl * 512 + ((chunk ^ (nl & 7)) << 4);
    *(uint4*)(catB + phys) = v;
  }
  __syncthreads();

  // ---- MFMA: wave w -> d in [64w, 64w+64), 64 nodes, K=256, W2 dbuf
  const int d0 = w * 64;
  f32x4 acc[4][4];
#pragma unroll
  for (int dt = 0; dt < 4; ++dt)
#pragma unroll
    for (int nt = 0; nt < 4; ++nt) acc[dt][nt] = (f32x4){0.f, 0.f, 0.f, 0.f};

  uint4 acur[4], anxt[4];
#pragma unroll
  for (int dt = 0; dt < 4; ++dt)
    acur[dt] = *(const uint4*)(W2b + (d0 + dt * 16 + lm) * CO + q * 8);

#pragma unroll
  for (int kt = 0; kt < 8; ++kt) {
    if (kt < 7) {
#pragma unroll
      for (int dt = 0; dt < 4; ++dt)
        anxt[dt] = *(const uint4*)(W2b + (d0 + dt * 16 + lm) * CO
                                   + (kt + 1) * 32 + q * 8);
    }
#pragma unroll
    for (int nt = 0; nt < 4; ++nt) {
      int nl = nt * 16 + lm;
      int chunk = kt * 4 + q;
      int phys = nl * 512 + ((chunk ^ (nl & 7)) << 4);
      bf16x8 bb = asbf8(*(const uint4*)(catB + phys));
#pragma unroll
      for (int dt = 0; dt < 4; ++dt)
        acc[dt][nt] = __builtin_amdgcn_mfma_f32_16x16x32_bf16(
            asbf8(acur[dt]), bb, acc[dt][nt], 0, 0, 0);
    }
#pragma unroll
    for (int dt = 0; dt < 4; ++dt) acur[dt] = anxt[dt];
  }

  // ---- epilogue: fp32 out [b][d][n]
#pragma unroll
  for (int dt = 0; dt < 4; ++dt) {
    int dbase = d0 + dt * 16 + q * 4;
    float4 bi = *(const float4*)(b2 + dbase);
    float bv[4] = {bi.x, bi.y, bi.z, bi.w};
#pragma unroll
    for (int nt = 0; nt < 4; ++nt) {
      int gn = n0 + nt * 16 + lm;
      if (gn < NODES) {
        float* op = out + ((size_t)(b * CO + dbase) * NODES) + gn;
#pragma unroll
        for (int r = 0; r < 4; ++r)
          op[(size_t)r * NODES] = fmaxf(acc[dt][nt][r] + bv[r], 0.f);
      }
    }
  }
}

// ---------------------------------------------------------------------------
extern "C" void kernel_launch(void* const* d_in, const int* in_sizes, int n_in,
                              void* d_out, int out_size, void* d_ws, size_t ws_size,
                              hipStream_t stream) {
  const float* x  = (const float*)d_in[0];
  const int*   ei = (const int*)d_in[1];   // (2,B,N,K); first half = targets
  const float* W1 = (const float*)d_in[2];
  const float* b1 = (const float*)d_in[3];
  const float* Wp = (const float*)d_in[4];
  const float* bp = (const float*)d_in[5];
  const float* W2 = (const float*)d_in[6];
  const float* b2 = (const float*)d_in[7];
  float* out = (float*)d_out;

  unsigned short* ws  = (unsigned short*)d_ws;
  unsigned short* h_t = ws;                                   // [B][N][128] bf16
  unsigned short* z_t = h_t + (size_t)BATCH * NODES * CH;     // [B][N][128] bf16
  unsigned short* W1b = z_t + (size_t)BATCH * NODES * CH;
  unsigned short* Wpb = W1b + CH * CH;
  unsigned short* W2b = Wpb + CH * CH;
  unsigned short* zm  = W2b + CO * 2 * CH;                    // [B][N][128] bf16

  prep<<<96, 256, 0, stream>>>(W1, Wp, W2, W1b, Wpb, W2b);

  const int NT = (NODES + 63) / 64;   // 157
  fused_hz<<<dim3(NT, BATCH), 256, 0, stream>>>(W1b, b1, Wpb, bp, x, h_t, z_t);
  gmax_kernel<<<BATCH * NT, 256, 0, stream>>>(z_t, ei, zm);
  out_gemm<<<BATCH * NT, 256, 0, stream>>>(h_t, zm, W2b, b2, out);
}